// Round 3
// baseline (1173.998 us; speedup 1.0000x reference)
//
#include <hip/hip_runtime.h>

// LogEig of 32768 SPD 32x32 fp32 matrices via one-sided Jacobi.
//
// v4: v3b (odd-even transposition + DPP exchange) + two VALU-count cuts.
// v3b measured 1120 us, VALUBusy 91% -> pure VALU-issue bound; only
// instruction count matters now. Changes:
//  (a) partner columns kept in regs across the odd round (o2[16]) -- kills
//      the 32-mov DPP refetch per odd round (~5% of main-loop issue).
//      __launch_bounds__(64,3) raises the VGPR budget to ~170 so the extra
//      32 regs stay in the register file (occupancy already ~3 waves/SIMD).
//  (b) convergence early-exit: Jacobi is quadratically convergent; once a
//      full sweep sees every normalized off-diagonal dot^2 <= 1e-6*gpp*gqq,
//      further sweeps are no-ops. Wave-wide __all over all 4 matrices.
//      Normalized (not absolute) criterion protects the lambda~1e-3
//      jitter-floor eigenvalues whose logs dominate the error budget.
//      Tail lane excluded (its dot is garbage by construction).
//
// Structure recap: 1 block = 1 wave = 4 matrices; 16 lanes/matrix; lane
// `sub` owns columns at positions (2*sub, 2*sub+1). Even rounds rotate the
// lane-local pair (zero communication). Odd rounds pair (pos 2s+1, 2s+2):
// fetch partner with DPP row_shl:1 (lane i <- i+1), ship the updated column
// back with row_shr:1 (lane i <- i-1). Always-swap => odd-even transposition
// covers all 496 pairs exactly once per 32-round sweep. DPP rows (16 lanes)
// never cross matrix boundaries. Main loop issues ZERO DS instructions.

typedef float v2f __attribute__((ext_vector_type(2)));

#define SWEEPS 10
#define TOL2   1e-6f   // exit when dot^2 <= TOL2 * gpp * gqq for a full sweep

static __device__ __forceinline__ float dpp_next(float v) {
    // lane i <- lane i+1 within its 16-lane row (row_shl:1).
    // Row tail (lane 15) has no source -> bound_ctrl=false keeps own value.
    return __builtin_bit_cast(float, __builtin_amdgcn_update_dpp(
        __builtin_bit_cast(int, v), __builtin_bit_cast(int, v),
        0x101 /*row_shl:1*/, 0xF, 0xF, false));
}
static __device__ __forceinline__ float dpp_ship(float oldv, float srcv) {
    // lane i <- srcv from lane i-1 within its row (row_shr:1).
    // Row head (lane 0) has no source -> keeps oldv (position 0 idle).
    return __builtin_bit_cast(float, __builtin_amdgcn_update_dpp(
        __builtin_bit_cast(int, oldv), __builtin_bit_cast(int, srcv),
        0x111 /*row_shr:1*/, 0xF, 0xF, false));
}

static __device__ __forceinline__ void make_rot(float dot, float gpp, float gqq,
                                                float& cr, float& sr) {
    // Jacobi rotation zeroing Gram(p,q); small root t of t^2 + 2*tau*t - 1 = 0.
    const float tau = (gqq - gpp) * 0.5f * __builtin_amdgcn_rcpf(dot);
    const float at  = fabsf(tau);
    float t = __builtin_amdgcn_rcpf(at + __builtin_amdgcn_sqrtf(fmaf(at, at, 1.f)));
    t = copysignf(t, tau);
    if (fabsf(dot) < 1e-37f) t = 0.f;   // skip / kill 0/0 NaN
    cr = __builtin_amdgcn_rsqf(fmaf(t, t, 1.f));
    sr = t * cr;
}

__global__ __launch_bounds__(64, 3) void logeig_kernel(const float* __restrict__ P,
                                                       float* __restrict__ out,
                                                       int nmat) {
    const int lane = threadIdx.x;     // 0..63
    const int sub  = lane & 15;       // lane within matrix
    const int mg   = lane >> 4;       // matrix slot within wave (0..3)
    int mat = blockIdx.x * 4 + mg;
    if (mat >= nmat) mat = nmat - 1;

    // Load columns 2*sub and 2*sub+1 (P symmetric -> column == row, contiguous).
    v2f X[16], Y[16];
    {
        const float4* s4 =
            reinterpret_cast<const float4*>(P + (size_t)mat * 1024 + (size_t)sub * 64);
        #pragma unroll
        for (int k = 0; k < 8; ++k) {
            float4 v = s4[k];
            X[2*k]   = (v2f){v.x, v.y};
            X[2*k+1] = (v2f){v.z, v.w};
        }
        #pragma unroll
        for (int k = 0; k < 8; ++k) {
            float4 v = s4[8 + k];
            Y[2*k]   = (v2f){v.x, v.y};
            Y[2*k+1] = (v2f){v.z, v.w};
        }
    }

    const bool tail = (sub == 15);    // its Y = position 31: idle in odd rounds

    #pragma unroll 1
    for (int sweep = 0; sweep < SWEEPS; ++sweep) {
        int big = 0;   // any rotation this sweep above convergence tolerance?
        #pragma unroll 1
        for (int rr = 0; rr < 16; ++rr) {
            // ---------- even round: local pair (u = X @ pos 2s, v = Y @ pos 2s+1)
            {
                v2f dA={0,0}, dB={0,0}, pA={0,0}, pB={0,0}, qA={0,0}, qB={0,0};
                #pragma unroll
                for (int k = 0; k < 16; k += 2) {
                    dA += X[k]   * Y[k];
                    pA += X[k]   * X[k];
                    qA += Y[k]   * Y[k];
                    dB += X[k+1] * Y[k+1];
                    pB += X[k+1] * X[k+1];
                    qB += Y[k+1] * Y[k+1];
                }
                v2f dT = dA + dB, pT = pA + pB, qT = qA + qB;
                const float dot = dT[0] + dT[1];
                const float gpp = pT[0] + pT[1];
                const float gqq = qT[0] + qT[1];
                big |= (dot * dot > TOL2 * gpp * gqq);
                float cr, sr;
                make_rot(dot, gpp, gqq, cr, sr);
                // always-swap: pos 2s <- v' = cr*Y + sr*X ; pos 2s+1 <- u' = cr*X - sr*Y
                #pragma unroll
                for (int k = 0; k < 16; ++k) {
                    v2f xo = X[k];
                    X[k] = cr * Y[k] + sr * xo;
                    Y[k] = cr * xo  - sr * Y[k];
                }
            }
            // ---------- odd round: pair (u = Y_s @ pos 2s+1, v = X_{s+1} @ pos 2s+2)
            {
                v2f o2[16];                 // partner column, fetched ONCE
                v2f dA={0,0}, dB={0,0}, pA={0,0}, pB={0,0}, qA={0,0}, qB={0,0};
                #pragma unroll
                for (int k = 0; k < 16; ++k) {
                    v2f o;
                    o[0] = dpp_next(X[k][0]);
                    o[1] = dpp_next(X[k][1]);
                    o2[k] = o;
                    if (k & 1) { dB += Y[k] * o; qB += o * o; pB += Y[k] * Y[k]; }
                    else       { dA += Y[k] * o; qA += o * o; pA += Y[k] * Y[k]; }
                }
                v2f dT = dA + dB, pT = pA + pB, qT = qA + qB;
                const float dot = dT[0] + dT[1];
                const float gpp = pT[0] + pT[1];
                const float gqq = qT[0] + qT[1];
                big |= (!tail && (dot * dot > TOL2 * gpp * gqq));
                float cr, sr;
                make_rot(dot, gpp, gqq, cr, sr);
                // boundary: position 31 (tail lane's Y) is unpaired -> (cr,sr)=(0,1)
                // makes Y' = Y exactly; its shipped u' dies at the row boundary.
                cr = tail ? 0.f : cr;
                sr = tail ? 1.f : sr;
                #pragma unroll
                for (int k = 0; k < 16; ++k) {
                    const v2f o  = o2[k];
                    const v2f yo = Y[k];
                    Y[k] = cr * o  + sr * yo;   // v' stays at pos 2s+1
                    v2f u = cr * yo - sr * o;   // u' ships to pos 2s+2 (lane s+1's X)
                    X[k][0] = dpp_ship(X[k][0], u[0]);   // lane 0 keeps X (pos 0 idle)
                    X[k][1] = dpp_ship(X[k][1], u[1]);
                }
            }
        }
        // Whole wave (all 4 matrices) converged this sweep -> remaining sweeps
        // are identity rotations; quadratic convergence makes this safe.
        if (__all(big == 0)) break;
    }

    // ---------- epilogue: sigma, log, normalize; X = sum_c l_c u_c u_c^T ----------
    float nx2, ny2;
    {
        v2f a={0,0}, b={0,0};
        #pragma unroll
        for (int k = 0; k < 16; k += 2) { a += X[k]*X[k]; b += X[k+1]*X[k+1]; }
        v2f t = a + b; nx2 = t[0] + t[1];
    }
    {
        v2f a={0,0}, b={0,0};
        #pragma unroll
        for (int k = 0; k < 16; k += 2) { a += Y[k]*Y[k]; b += Y[k+1]*Y[k+1]; }
        v2f t = a + b; ny2 = t[0] + t[1];
    }
    const float invx = __builtin_amdgcn_rsqf(nx2);               // 1/sigma
    const float invy = __builtin_amdgcn_rsqf(ny2);
    const float lgx  = 0.34657359f * __builtin_amdgcn_logf(nx2); // ln(sigma)
    const float lgy  = 0.34657359f * __builtin_amdgcn_logf(ny2);

    // One matrix per phase; 4.6 KB total so occupancy is VGPR-limited, not LDS.
    // Row stride 36 floats keeps every 16-float half 16B-aligned; log(eig) is
    // stashed in the pad at [c][33].
    __shared__ __align__(16) float S[32][36];

    const int r = lane >> 1;       // output row this lane accumulates
    const int h = lane & 1;        // which 16-float half of that row

    #pragma unroll 1
    for (int ph = 0; ph < 4; ++ph) {
        __syncthreads();           // protect S reuse across phases
        if (mg == ph) {
            #pragma unroll
            for (int k = 0; k < 16; ++k) {
                *reinterpret_cast<v2f*>(&S[2*sub][2*k])   = X[k] * invx;
                *reinterpret_cast<v2f*>(&S[2*sub+1][2*k]) = Y[k] * invy;
            }
            S[2*sub][33]   = lgx;
            S[2*sub+1][33] = lgy;
        }
        __syncthreads();

        // All 64 lanes cooperate: lane computes half-row (r, h) of matrix ph.
        v2f acc[8];
        #pragma unroll
        for (int j = 0; j < 8; ++j) acc[j] = (v2f){0.f, 0.f};
        #pragma unroll 4
        for (int c = 0; c < 32; ++c) {
            const float m = S[c][r] * S[c][33];          // u_c[r] * log(lambda_c)
            const float4* row4 = reinterpret_cast<const float4*>(&S[c][h * 16]);
            #pragma unroll
            for (int j4 = 0; j4 < 4; ++j4) {
                float4 v = row4[j4];
                acc[2*j4]   += m * (v2f){v.x, v.y};
                acc[2*j4+1] += m * (v2f){v.z, v.w};
            }
        }
        int m2 = blockIdx.x * 4 + ph;
        if (m2 >= nmat) m2 = nmat - 1;
        // lane -> (r,h): consecutive lanes write consecutive 16B -> fully coalesced.
        float4* d4 = reinterpret_cast<float4*>(out + (size_t)m2 * 1024 +
                                               (size_t)r * 32 + h * 16);
        #pragma unroll
        for (int j4 = 0; j4 < 4; ++j4)
            d4[j4] = make_float4(acc[2*j4][0], acc[2*j4][1],
                                 acc[2*j4+1][0], acc[2*j4+1][1]);
    }
}

extern "C" void kernel_launch(void* const* d_in, const int* in_sizes, int n_in,
                              void* d_out, int out_size, void* d_ws, size_t ws_size,
                              hipStream_t stream) {
    const float* P = (const float*)d_in[0];
    float* out = (float*)d_out;
    const int nmat = in_sizes[0] / 1024;     // 32768
    const int nblocks = (nmat + 3) / 4;      // 4 matrices per 64-thread block
    logeig_kernel<<<nblocks, 64, 0, stream>>>(P, out, nmat);
}